// Round 17
// baseline (538.231 us; speedup 1.0000x reference)
//
#include <hip/hip_runtime.h>
#include <math.h>

#define B    512
#define L    1024
#define K    8
#define NR   512
#define S    20
#define EXT  26
#define SS   (S*S)            // 400
#define PD   24               // padded matrix dim (zero pad is matmul-self-consistent)
#define PDSQ (PD*PD)          // 576
#define ROWF (K*EXT)          // 208 floats per (b,l)
#define ROWQ ((EXT*ROWF)/4)   // 1352 float4 per b in the LUT
#define BROW (L*ROWF)         // 212992 floats per b
#define UPB  (BROW/4)         // 53248 f4 per b

typedef float f4 __attribute__((ext_vector_type(4)));

__device__ __forceinline__ float softplusf(float x) {
    return fmaxf(x, 0.0f) + log1pf(expf(-fabsf(x)));
}

// wave-local ordering fence: per-wave DS ops complete in order on CDNA, so
// for a wave working on its OWN LDS patch this replaces __syncthreads.
__device__ __forceinline__ void wave_fence() {
    __builtin_amdgcn_wave_barrier();
}

// ---------------------------------------------------------------------------
// Kernel 1: expm -> LUT in d_ws. VERBATIM the r2 kernel (verified passed,
// absmax 1.22e-4, ws_size sufficient). Block = one b; wave w owns matrix k=w.
// ---------------------------------------------------------------------------
__global__ __launch_bounds__(512, 2) void expm_kernel(
    const int*   __restrict__ rate_indices,  // B
    const float* __restrict__ tau_kernel,    // NR
    const float* __restrict__ exch,          // K,S,S
    const float* __restrict__ freq,          // S
    float*       __restrict__ lut)           // B,26,208
{
    __shared__ __align__(16) float M[K][2][PDSQ];   // 36864 B
    __shared__ __align__(16) float Row[EXT*ROWF];   // 21632 B
    __shared__ float diag_sh[K][S];
    __shared__ float mue_sh[K];

    const int b    = blockIdx.x;
    const int t    = threadIdx.x;
    const int w    = t >> 6;          // wave id == matrix k
    const int lane = t & 63;
    const int li = lane >> 3, lj = lane & 7;
    const int r0 = 3*li, c0 = 3*lj;   // 3x3 tile origin in 24x24

    // ---- phase 0: Row LUT init (cells tiles never write) ----
    for (int e = t; e < EXT*ROWF; e += 512) {
        int row = e / ROWF, c = e - row*ROWF;
        int k = c / EXT, s = c - k*EXT;
        (void)k;
        if (row < S) {
            if (s >= S) Row[e] = 0.f;              // pad cols only; P cells skipped
        } else {
            Row[e] = (s == row) ? 1.f : 0.f;       // one-hot rows
        }
    }
    float* M0 = &M[w][0][0];
    float* M1 = &M[w][1][0];
    for (int e = lane; e < 2*PDSQ; e += 64) M0[e] = 0.f;  // zero both buffers
    float tau = softplusf(tau_kernel[rate_indices[b]]);
    wave_fence();

    // ---- phase 1: build A = (Q_w / mue) * tau / 2^6 in M0 ----
    const float* E = exch + w * SS;
    for (int e = lane; e < SS; e += 64) {
        int r = e / S, c = e - r*S;
        float v = 0.f;
        if (r != c)
            v = softplusf(0.5f * (E[r*S + c] + E[c*S + r])) * freq[c];
        M0[r*PD + c] = v;
    }
    wave_fence();
    if (lane < S) {
        float d = 0.f;
        #pragma unroll
        for (int j = 0; j < S; ++j) d += M0[lane*PD + j];
        diag_sh[w][lane] = d;
    }
    wave_fence();
    if (lane == 0) {
        float m = 0.f;
        #pragma unroll
        for (int s = 0; s < S; ++s) m += freq[s] * diag_sh[w][s];
        mue_sh[w] = fmaxf(m, 1e-16f);
    }
    wave_fence();
    {
        float scale = tau * 0.015625f;
        float mue   = mue_sh[w];
        for (int e = lane; e < SS; e += 64) {
            int r = e / S, c = e - r*S;
            float v = (r == c) ? -diag_sh[w][r] : M0[r*PD + c];
            M0[r*PD + c] = (v / mue) * scale;
        }
    }
    wave_fence();

    // ---- expm: A cols in regs, P=I+A, order-10 Taylor, 6 squarings ----
    float Ac[S][3];
    #pragma unroll
    for (int j = 0; j < S; ++j) {
        #pragma unroll
        for (int d = 0; d < 3; ++d)
            Ac[j][d] = M0[j*PD + c0 + d];
    }

    float P[3][3];
    #pragma unroll
    for (int dr = 0; dr < 3; ++dr)
        #pragma unroll
        for (int dc = 0; dc < 3; ++dc) {
            int r = r0 + dr, c = c0 + dc;
            P[dr][dc] = M0[r*PD + c] + ((r == c && r < S) ? 1.f : 0.f);
        }

    const float* Tc = M0;
    float* Tn = M1;
    #pragma unroll 1
    for (int i = 2; i <= 10; ++i) {
        float C[3][3] = {{0.f,0.f,0.f},{0.f,0.f,0.f},{0.f,0.f,0.f}};
        #pragma unroll
        for (int jc = 0; jc < 5; ++jc) {
            float4 a0 = *(const float4*)&Tc[(r0+0)*PD + 4*jc];
            float4 a1 = *(const float4*)&Tc[(r0+1)*PD + 4*jc];
            float4 a2 = *(const float4*)&Tc[(r0+2)*PD + 4*jc];
            float t0[4] = {a0.x, a0.y, a0.z, a0.w};
            float t1[4] = {a1.x, a1.y, a1.z, a1.w};
            float t2[4] = {a2.x, a2.y, a2.z, a2.w};
            #pragma unroll
            for (int dj = 0; dj < 4; ++dj) {
                int j = 4*jc + dj;
                #pragma unroll
                for (int dc = 0; dc < 3; ++dc) {
                    C[0][dc] = fmaf(t0[dj], Ac[j][dc], C[0][dc]);
                    C[1][dc] = fmaf(t1[dj], Ac[j][dc], C[1][dc]);
                    C[2][dc] = fmaf(t2[dj], Ac[j][dc], C[2][dc]);
                }
            }
        }
        float inv = 1.0f / (float)i;
        #pragma unroll
        for (int dr = 0; dr < 3; ++dr)
            #pragma unroll
            for (int dc = 0; dc < 3; ++dc) {
                C[dr][dc] *= inv;
                P[dr][dc] += C[dr][dc];
                Tn[(r0+dr)*PD + c0 + dc] = C[dr][dc];
            }
        wave_fence();
        float* tmp = (float*)Tc; Tc = Tn; Tn = tmp;
    }

    #pragma unroll 1
    for (int sq = 0; sq < 6; ++sq) {
        #pragma unroll
        for (int dr = 0; dr < 3; ++dr)
            #pragma unroll
            for (int dc = 0; dc < 3; ++dc)
                Tn[(r0+dr)*PD + c0 + dc] = P[dr][dc];
        wave_fence();
        const float* Pb = Tn;
        float C[3][3] = {{0.f,0.f,0.f},{0.f,0.f,0.f},{0.f,0.f,0.f}};
        #pragma unroll
        for (int jc = 0; jc < 5; ++jc) {
            float4 a0 = *(const float4*)&Pb[(r0+0)*PD + 4*jc];
            float4 a1 = *(const float4*)&Pb[(r0+1)*PD + 4*jc];
            float4 a2 = *(const float4*)&Pb[(r0+2)*PD + 4*jc];
            float t0[4] = {a0.x, a0.y, a0.z, a0.w};
            float t1[4] = {a1.x, a1.y, a1.z, a1.w};
            float t2[4] = {a2.x, a2.y, a2.z, a2.w};
            float cb[4][3];
            #pragma unroll
            for (int dj = 0; dj < 4; ++dj)
                #pragma unroll
                for (int dc = 0; dc < 3; ++dc)
                    cb[dj][dc] = Pb[(4*jc + dj)*PD + c0 + dc];
            #pragma unroll
            for (int dj = 0; dj < 4; ++dj)
                #pragma unroll
                for (int dc = 0; dc < 3; ++dc) {
                    C[0][dc] = fmaf(t0[dj], cb[dj][dc], C[0][dc]);
                    C[1][dc] = fmaf(t1[dj], cb[dj][dc], C[1][dc]);
                    C[2][dc] = fmaf(t2[dj], cb[dj][dc], C[2][dc]);
                }
        }
        #pragma unroll
        for (int dr = 0; dr < 3; ++dr)
            #pragma unroll
            for (int dc = 0; dc < 3; ++dc)
                P[dr][dc] = C[dr][dc];
        float* tmp = (float*)Tc; Tc = Tn; Tn = tmp;
        wave_fence();
    }

    // ---- P tiles -> Row LUT ----
    #pragma unroll
    for (int dr = 0; dr < 3; ++dr) {
        int r = r0 + dr; if (r >= S) continue;
        #pragma unroll
        for (int dc = 0; dc < 3; ++dc) {
            int c = c0 + dc; if (c >= S) continue;
            Row[r*ROWF + w*EXT + c] = P[dr][dc];
        }
    }
    __syncthreads();

    // ---- LUT writeback: 21.6 KB coalesced float4 copy to d_ws ----
    f4* dst = (f4*)lut + (size_t)b * ROWQ;
    const f4* src = (const f4*)Row;
    for (int e = t; e < ROWQ; e += 512) dst[e] = src[e];
}

// ---------------------------------------------------------------------------
// Kernel 2: rolling-window stream, FULL parallelism + 2-deep pipeline.
// 1664 blocks x 256 = 425984 threads, all co-resident (~26 waves/CU, no LDS,
// <=64 VGPR). Thread owns fixed (db = t/53248 in [0,8), u = t%53248); loops
// it = 0..63 over b = it*8 + db. Per iteration the WHOLE GPU writes one
// contiguous 6.7 MB output window (8 b's) -> per HBM channel, pending writes
// cluster in a tiny range -> controller reorders row-sequentially (the
// fillBufferAligned pattern, 6.2 TB/s). Prior slow variants drained ~64
// interleaved per-XCD streams (row thrash, 2.7 TB/s). Unlike r10 (53k
// threads, serial dependent chain), gathers are pipelined: inp prefetched
// 2 iters ahead, LUT value 1 iter ahead -> stores never wait on the gather.
// ---------------------------------------------------------------------------
__global__ __launch_bounds__(256, 8) void stream3_kernel(
    const int*   __restrict__ inputs,   // B,L
    const float* __restrict__ lut,      // B,26,208
    float*       __restrict__ out)      // B,L,208
{
    const int t  = blockIdx.x * 256 + threadIdx.x;   // 0..425983
    const int db = t / UPB;                          // 0..7
    const int u  = t - db * UPB;                     // 0..53247
    const int l  = u / 52;
    const int q  = u - l * 52;

    const f4* lut4 = (const f4*)lut;
    f4* out4 = (f4*)out;

    // pipeline prologue: v = value[it=0], inpA = inp for it=1
    int inp0 = inputs[db * L + l];                   // b = db       (it=0)
    int inpA = inputs[(8 + db) * L + l];             // b = 8+db     (it=1)
    f4 v = lut4[db * ROWQ + inp0 * 52 + q];

    #pragma unroll 1
    for (int it = 0; it < 64; ++it) {
        const int i1 = (it + 1 < 64) ? (it + 1) : 63;   // clamp (tail loads harmless)
        const int i2 = (it + 2 < 64) ? (it + 2) : 63;
        f4  vn   = lut4[(i1 * 8 + db) * ROWQ + inpA * 52 + q];  // value[it+1]
        int inpN = inputs[(i2 * 8 + db) * L + l];               // inp[it+2]
        out4[(size_t)(it * 8 + db) * UPB + u] = v;              // window store
        v = vn;
        inpA = inpN;
    }
}

// ---------------------------------------------------------------------------
extern "C" void kernel_launch(void* const* d_in, const int* in_sizes, int n_in,
                              void* d_out, int out_size, void* d_ws, size_t ws_size,
                              hipStream_t stream) {
    const int*   inputs  = (const int*)  d_in[0];  // (B,L) int32
    const int*   rate_ix = (const int*)  d_in[1];  // (B,) int32
    const float* tau_k   = (const float*)d_in[2];  // (NR,) f32
    const float* exch    = (const float*)d_in[3];  // (K,S,S) f32
    const float* freq    = (const float*)d_in[4];  // (S,) f32
    float* out = (float*)d_out;
    float* lut = (float*)d_ws;                     // needs 11,075,584 B (r2-verified)

    (void)in_sizes; (void)n_in; (void)out_size; (void)ws_size;

    expm_kernel<<<B, 512, 0, stream>>>(rate_ix, tau_k, exch, freq, lut);
    stream3_kernel<<<1664, 256, 0, stream>>>(inputs, lut, out);
}

// Round 20
// 468.427 us; speedup vs baseline: 1.1490x; 1.1490x over previous
//
#include <hip/hip_runtime.h>
#include <math.h>

#define B    512
#define L    1024
#define K    8
#define NR   512
#define S    20
#define EXT  26
#define SS   (S*S)            // 400
#define PD   24               // padded matrix dim (zero pad is matmul-self-consistent)
#define PDSQ (PD*PD)          // 576
#define ROWF (K*EXT)          // 208 floats per (b,l)
#define BROW (L*ROWF)         // 212992 floats per b

typedef float f4 __attribute__((ext_vector_type(4)));

__device__ __forceinline__ float softplusf(float x) {
    return fmaxf(x, 0.0f) + log1pf(expf(-fabsf(x)));
}

// wave-local ordering fence: per-wave DS ops complete in order on CDNA, so
// for a wave working on its OWN LDS patch this replaces __syncthreads.
__device__ __forceinline__ void wave_fence() {
    __builtin_amdgcn_wave_barrier();
}

// ---------------------------------------------------------------------------
// Fused kernel = round-0 verified structure (477.98us best), with TWO
// expm-phase LDS-throughput cuts (stream phase untouched):
//  (a) Taylor order 10 -> 8 (i=2..8). Added truncation <= ||A||^9/9! * 2^6
//      <= 2.9e-4 at ||A||=1.06 (r3 passed at absmax 3.9e-3 -> safe margin).
//  (b) squarings: write P into Tn AND P^T into the DEAD Tc buffer, then read
//      the B-operand as ROWS of P^T via ds_read_b128 — removes the 60 scalar
//      ds_read_b32 column reads per stage (the dominant LDS cost).
// Phase model: expm was LDS-pipe-bound (~580 cyc/sq-stage/wave); now ~470,
// and 2 fewer Taylor stages. Predicted expm ~40 -> ~31us.
// ---------------------------------------------------------------------------
__global__ __launch_bounds__(512, 2) void fused_kernel(
    const int*   __restrict__ inputs,        // B,L
    const int*   __restrict__ rate_indices,  // B
    const float* __restrict__ tau_kernel,    // NR
    const float* __restrict__ exch,          // K,S,S
    const float* __restrict__ freq,          // S
    float* __restrict__ out)                 // B,L,208
{
    __shared__ __align__(16) float M[K][2][PDSQ];   // 36864 B
    __shared__ __align__(16) float Row[EXT*ROWF];   // 21632 B
    __shared__ int   inp_sh[L];                     // 4096 B
    __shared__ float diag_sh[K][S];
    __shared__ float mue_sh[K];

    const int b    = blockIdx.x;
    const int t    = threadIdx.x;
    const int w    = t >> 6;          // wave id == matrix k
    const int lane = t & 63;
    const int li = lane >> 3, lj = lane & 7;
    const int r0 = 3*li, c0 = 3*lj;   // 3x3 tile origin in 24x24

    // ---- phase 0 (no cross-wave ordering needed until the final barrier) ----
    for (int u = t; u < L; u += 512) inp_sh[u] = inputs[b*L + u];
    for (int e = t; e < EXT*ROWF; e += 512) {
        int row = e / ROWF, c = e - row*ROWF;
        int k = c / EXT, s = c - k*EXT;
        (void)k;
        if (row < S) {
            if (s >= S) Row[e] = 0.f;              // pad cols only; P cells skipped
        } else {
            Row[e] = (s == row) ? 1.f : 0.f;       // one-hot rows
        }
    }
    float* M0 = &M[w][0][0];
    float* M1 = &M[w][1][0];
    for (int e = lane; e < 2*PDSQ; e += 64) M0[e] = 0.f;  // zero both buffers
    // tau: uniform loads, computed redundantly in every lane
    float tau = softplusf(tau_kernel[rate_indices[b]]);
    wave_fence();

    // ---- phase 1: build A = (Q_w / mue) * tau / 2^6 in M0 ----
    const float* E = exch + w * SS;
    for (int e = lane; e < SS; e += 64) {
        int r = e / S, c = e - r*S;
        float v = 0.f;
        if (r != c)
            v = softplusf(0.5f * (E[r*S + c] + E[c*S + r])) * freq[c];
        M0[r*PD + c] = v;
    }
    wave_fence();
    if (lane < S) {
        float d = 0.f;
        #pragma unroll
        for (int j = 0; j < S; ++j) d += M0[lane*PD + j];
        diag_sh[w][lane] = d;
    }
    wave_fence();
    if (lane == 0) {
        float m = 0.f;
        #pragma unroll
        for (int s = 0; s < S; ++s) m += freq[s] * diag_sh[w][s];
        mue_sh[w] = fmaxf(m, 1e-16f);
    }
    wave_fence();
    {
        float scale = tau * 0.015625f;
        float mue   = mue_sh[w];
        for (int e = lane; e < SS; e += 64) {
            int r = e / S, c = e - r*S;
            float v = (r == c) ? -diag_sh[w][r] : M0[r*PD + c];
            M0[r*PD + c] = (v / mue) * scale;
        }
    }
    wave_fence();

    // ---- expm: A cols in regs, P=I+A, order-8 Taylor, 6 squarings ----
    float Ac[S][3];
    #pragma unroll
    for (int j = 0; j < S; ++j) {
        #pragma unroll
        for (int d = 0; d < 3; ++d)
            Ac[j][d] = M0[j*PD + c0 + d];
    }

    float P[3][3];
    #pragma unroll
    for (int dr = 0; dr < 3; ++dr)
        #pragma unroll
        for (int dc = 0; dc < 3; ++dc) {
            int r = r0 + dr, c = c0 + dc;
            P[dr][dc] = M0[r*PD + c] + ((r == c && r < S) ? 1.f : 0.f);
        }

    const float* Tc = M0;
    float* Tn = M1;
    #pragma unroll 1
    for (int i = 2; i <= 8; ++i) {
        float C[3][3] = {{0.f,0.f,0.f},{0.f,0.f,0.f},{0.f,0.f,0.f}};
        #pragma unroll
        for (int jc = 0; jc < 5; ++jc) {
            float4 a0 = *(const float4*)&Tc[(r0+0)*PD + 4*jc];
            float4 a1 = *(const float4*)&Tc[(r0+1)*PD + 4*jc];
            float4 a2 = *(const float4*)&Tc[(r0+2)*PD + 4*jc];
            float t0[4] = {a0.x, a0.y, a0.z, a0.w};
            float t1[4] = {a1.x, a1.y, a1.z, a1.w};
            float t2[4] = {a2.x, a2.y, a2.z, a2.w};
            #pragma unroll
            for (int dj = 0; dj < 4; ++dj) {
                int j = 4*jc + dj;
                #pragma unroll
                for (int dc = 0; dc < 3; ++dc) {
                    C[0][dc] = fmaf(t0[dj], Ac[j][dc], C[0][dc]);
                    C[1][dc] = fmaf(t1[dj], Ac[j][dc], C[1][dc]);
                    C[2][dc] = fmaf(t2[dj], Ac[j][dc], C[2][dc]);
                }
            }
        }
        float inv = 1.0f / (float)i;
        #pragma unroll
        for (int dr = 0; dr < 3; ++dr)
            #pragma unroll
            for (int dc = 0; dc < 3; ++dc) {
                C[dr][dc] *= inv;
                P[dr][dc] += C[dr][dc];
                Tn[(r0+dr)*PD + c0 + dc] = C[dr][dc];
            }
        wave_fence();
        float* tmp = (float*)Tc; Tc = Tn; Tn = tmp;
    }

    // ---- squarings: P <- P*P, B-operand via transposed copy in dead buffer.
    // Both Tn and Tct are fully rewritten each iteration (tiles cover 24x24),
    // so no buffer swap is needed.
    float* Tsq = Tn;            // row-major P
    float* Tct = (float*)Tc;    // transposed P (dead Taylor buffer)
    #pragma unroll 1
    for (int sq = 0; sq < 6; ++sq) {
        #pragma unroll
        for (int dr = 0; dr < 3; ++dr)
            #pragma unroll
            for (int dc = 0; dc < 3; ++dc) {
                Tsq[(r0+dr)*PD + c0 + dc] = P[dr][dc];
                Tct[(c0+dc)*PD + r0 + dr] = P[dr][dc];
            }
        wave_fence();
        float C[3][3] = {{0.f,0.f,0.f},{0.f,0.f,0.f},{0.f,0.f,0.f}};
        #pragma unroll
        for (int jc = 0; jc < 5; ++jc) {
            float4 a0 = *(const float4*)&Tsq[(r0+0)*PD + 4*jc];
            float4 a1 = *(const float4*)&Tsq[(r0+1)*PD + 4*jc];
            float4 a2 = *(const float4*)&Tsq[(r0+2)*PD + 4*jc];
            float4 b0 = *(const float4*)&Tct[(c0+0)*PD + 4*jc];
            float4 b1 = *(const float4*)&Tct[(c0+1)*PD + 4*jc];
            float4 b2 = *(const float4*)&Tct[(c0+2)*PD + 4*jc];
            float ta[3][4] = {{a0.x,a0.y,a0.z,a0.w},
                              {a1.x,a1.y,a1.z,a1.w},
                              {a2.x,a2.y,a2.z,a2.w}};
            float tb[3][4] = {{b0.x,b0.y,b0.z,b0.w},
                              {b1.x,b1.y,b1.z,b1.w},
                              {b2.x,b2.y,b2.z,b2.w}};
            #pragma unroll
            for (int dj = 0; dj < 4; ++dj)
                #pragma unroll
                for (int dr = 0; dr < 3; ++dr)
                    #pragma unroll
                    for (int dc = 0; dc < 3; ++dc)
                        C[dr][dc] = fmaf(ta[dr][dj], tb[dc][dj], C[dr][dc]);
        }
        #pragma unroll
        for (int dr = 0; dr < 3; ++dr)
            #pragma unroll
            for (int dc = 0; dc < 3; ++dc)
                P[dr][dc] = C[dr][dc];
        wave_fence();
    }

    // ---- P tiles -> Row LUT (only r<20, c<20 cells; disjoint from init) ----
    #pragma unroll
    for (int dr = 0; dr < 3; ++dr) {
        int r = r0 + dr; if (r >= S) continue;
        #pragma unroll
        for (int dc = 0; dc < 3; ++dc) {
            int c = c0 + dc; if (c >= S) continue;
            Row[r*ROWF + w*EXT + c] = P[dr][dc];
        }
    }
    __syncthreads();   // the ONLY block-wide barrier

    // ---- phase 2: streaming store — VERBATIM round-0 (477.98us verified) ----
    int l0[13], qq[13];
    {
        int uu = t;
        #pragma unroll
        for (int j = 0; j < 13; ++j) {
            l0[j] = uu / 52;
            qq[j] = uu - l0[j] * 52;
            uu += 512;
        }
    }
    const f4* Row4 = (const f4*)Row;
    f4* out4 = (f4*)out + (size_t)b * (BROW/4);
    #pragma unroll 1
    for (int i = 0; i < 8; ++i) {
        int lbase = i << 7;          // 128*i
        int ubase = t + i * 6656;
        #pragma unroll
        for (int j = 0; j < 13; ++j) {
            int inp = inp_sh[l0[j] + lbase];
            out4[ubase + (j << 9)] = Row4[inp * 52 + qq[j]];
        }
    }
}

// ---------------------------------------------------------------------------
extern "C" void kernel_launch(void* const* d_in, const int* in_sizes, int n_in,
                              void* d_out, int out_size, void* d_ws, size_t ws_size,
                              hipStream_t stream) {
    const int*   inputs  = (const int*)  d_in[0];  // (B,L) int32
    const int*   rate_ix = (const int*)  d_in[1];  // (B,) int32
    const float* tau_k   = (const float*)d_in[2];  // (NR,) f32
    const float* exch    = (const float*)d_in[3];  // (K,S,S) f32
    const float* freq    = (const float*)d_in[4];  // (S,) f32
    float* out = (float*)d_out;

    (void)d_ws; (void)ws_size; (void)in_sizes; (void)n_in; (void)out_size;

    fused_kernel<<<B, 512, 0, stream>>>(inputs, rate_ix, tau_k, exch, freq, out);
}